// Round 4
// baseline (792.534 us; speedup 1.0000x reference)
//
#include <hip/hip_runtime.h>
#include <hip/hip_bf16.h>

#define S_LEN 2048
#define D_DIM 1024
#define NH    16
#define NEG_BIG (-1.0e30f)

typedef __attribute__((ext_vector_type(8))) short bf16x8;
typedef __attribute__((ext_vector_type(4))) float f32x4;

__device__ __forceinline__ float bf2f(unsigned short h) {
    union { unsigned int u; float f; } v; v.u = ((unsigned int)h) << 16; return v.f;
}
__device__ __forceinline__ unsigned short f2b(float f) {   // RNE f32->bf16 raw bits
    union { float f; unsigned int u; } v; v.f = f;
    unsigned int u = v.u;
    return (unsigned short)((u + 0x7FFFu + ((u >> 16) & 1u)) >> 16);
}

// dtype sniff: external buffers f32 or bf16? Examine 256 low-u16s of x.
// bf16 N(0,1) data: exponent field in [96,130] essentially always.
// f32 data: low u16 = random mantissa bits -> ~14% hit that range.
__global__ void sniff(const unsigned int* __restrict__ xw, int* __restrict__ flag) {
    int t = threadIdx.x;  // 64
    int cnt = 0;
    #pragma unroll
    for (int i = 0; i < 4; ++i) {
        unsigned int lo = xw[t * 4 + i] & 0xFFFFu;
        unsigned int e = (lo >> 7) & 0xFFu;
        cnt += (e >= 96u && e <= 130u) ? 1 : 0;
    }
    #pragma unroll
    for (int d = 1; d < 64; d <<= 1) cnt += __shfl_xor(cnt, d);
    if (t == 0) *flag = (cnt < 128) ? 1 : 0;   // 1 = external bufs are f32
}

// C[M,N] = A[M,K] * B[N,K]^T. Internal format bf16; external operands decoded per flag.
// aExt/bExt/cExt: operand lives in external (flag-typed) memory. which==2 fuses v-mix.
__global__ __launch_bounds__(256, 2)
void gemm_bt(const void* __restrict__ A,
             const void* __restrict__ B0, const void* __restrict__ B1, const void* __restrict__ B2,
             void* __restrict__ C0, void* __restrict__ C1, void* __restrict__ C2,
             const void* __restrict__ vmix, const void* __restrict__ lam,
             const int* __restrict__ flagp,
             int aExt, int bExt, int cExt, int K, int N)
{
    const int f32f = *flagp;
    const int aF32 = aExt & f32f, bF32 = bExt & f32f, cF32 = cExt & f32f;
    const int which = blockIdx.z;
    const void* B = (which == 0) ? B0 : ((which == 1) ? B1 : B2);
    void* C = (which == 0) ? C0 : ((which == 1) ? C1 : C2);
    const int tn = blockIdx.x * 128;
    const int tm = blockIdx.y * 128;

    __shared__ unsigned short As[128][40];
    __shared__ unsigned short Bs[128][40];

    const int t    = threadIdx.x;
    const int lane = t & 63;
    const int wave = t >> 6;
    const int wm   = (wave >> 1) * 64;
    const int wn   = (wave & 1) * 64;
    const int lrow = lane & 15;
    const int quad = lane >> 4;

    f32x4 acc[4][4];
    #pragma unroll
    for (int i = 0; i < 4; ++i)
        #pragma unroll
        for (int j = 0; j < 4; ++j) {
            f32x4 z = {0.f, 0.f, 0.f, 0.f};
            acc[i][j] = z;
        }

    for (int k0 = 0; k0 < K; k0 += 32) {
        #pragma unroll
        for (int rep = 0; rep < 2; ++rep) {
            int cc  = t + rep * 256;
            int row = cc >> 2;
            int col = (cc & 3) * 8;
            size_t aoff = (size_t)(tm + row) * K + k0 + col;
            size_t boff = (size_t)(tn + row) * K + k0 + col;
            uint4 pa, pb;
            if (aF32) {
                const float* ap = (const float*)A + aoff;
                float4 l = *(const float4*)ap, h = *(const float4*)(ap + 4);
                pa.x = f2b(l.x) | ((unsigned)f2b(l.y) << 16);
                pa.y = f2b(l.z) | ((unsigned)f2b(l.w) << 16);
                pa.z = f2b(h.x) | ((unsigned)f2b(h.y) << 16);
                pa.w = f2b(h.z) | ((unsigned)f2b(h.w) << 16);
            } else {
                pa = *(const uint4*)((const unsigned short*)A + aoff);
            }
            if (bF32) {
                const float* bp = (const float*)B + boff;
                float4 l = *(const float4*)bp, h = *(const float4*)(bp + 4);
                pb.x = f2b(l.x) | ((unsigned)f2b(l.y) << 16);
                pb.y = f2b(l.z) | ((unsigned)f2b(l.w) << 16);
                pb.z = f2b(h.x) | ((unsigned)f2b(h.y) << 16);
                pb.w = f2b(h.z) | ((unsigned)f2b(h.w) << 16);
            } else {
                pb = *(const uint4*)((const unsigned short*)B + boff);
            }
            *(uint4*)(&As[row][col]) = pa;
            *(uint4*)(&Bs[row][col]) = pb;
        }
        __syncthreads();
        bf16x8 af[4], bfr[4];
        #pragma unroll
        for (int i = 0; i < 4; ++i)
            af[i] = *(const bf16x8*)(&As[wm + i * 16 + lrow][quad * 8]);
        #pragma unroll
        for (int j = 0; j < 4; ++j)
            bfr[j] = *(const bf16x8*)(&Bs[wn + j * 16 + lrow][quad * 8]);
        #pragma unroll
        for (int i = 0; i < 4; ++i)
            #pragma unroll
            for (int j = 0; j < 4; ++j)
                acc[i][j] = __builtin_amdgcn_mfma_f32_16x16x32_bf16(af[i], bfr[j], acc[i][j], 0, 0, 0);
        __syncthreads();
    }

    const bool domix = (which == 2) && (vmix != nullptr);
    float lamf = 0.f;
    if (domix)
        lamf = f32f ? *(const float*)lam : bf2f(((const unsigned short*)lam)[0]);

    #pragma unroll
    for (int i = 0; i < 4; ++i) {
        #pragma unroll
        for (int j = 0; j < 4; ++j) {
            #pragma unroll
            for (int r = 0; r < 4; ++r) {
                int cm = tm + wm + i * 16 + quad * 4 + r;   // row = quad*4+reg (m89/m91)
                int cn = tn + wn + j * 16 + lrow;           // col = lane&15
                size_t idx = (size_t)cm * N + cn;
                float v = acc[i][j][r];
                if (domix) {
                    float vf = f32f ? ((const float*)vmix)[idx]
                                    : bf2f(((const unsigned short*)vmix)[idx]);
                    v = (1.f - lamf) * v + lamf * vf;
                }
                if (cF32) ((float*)C)[idx] = v;
                else      ((unsigned short*)C)[idx] = f2b(v);
            }
        }
    }
}

// fused per-head RMSNorm + RoPE, in place on internal bf16 buffers.
__global__ __launch_bounds__(256)
void norm_rope(unsigned short* __restrict__ Qb, unsigned short* __restrict__ Kb)
{
    unsigned short* X = (blockIdx.y == 0) ? Qb : Kb;
    const int t = threadIdx.x;
    const int wave = t >> 6, lane = t & 63;
    const int row = blockIdx.x * 4 + wave;
    const int s = row >> 4;
    const int h = row & 15;
    unsigned short* xp = X + (size_t)s * D_DIM + h * 64;

    float x = bf2f(xp[lane]);
    float ss = x * x;
    #pragma unroll
    for (int d = 1; d < 64; d <<= 1) ss += __shfl_xor(ss, d);
    float rms = rsqrtf(ss * (1.f / 64.f) + 1.1920929e-7f);
    float xn = x * rms;
    float part = __shfl_xor(xn, 32);
    int i = lane & 31;
    float inv = exp2f(-0.41524101186092030f * (float)i);     // 10000^(-2i/64)
    float ang = (float)s * inv;
    float sv, cv;
    sincosf(ang, &sv, &cv);
    float o = xn * cv + ((lane < 32) ? part * sv : -part * sv);
    xp[lane] = f2b(o);
}

// flash-style causal attention on internal bf16 buffers. Ob may alias Qb.
__global__ __launch_bounds__(256, 2)
void attn(const unsigned short* Qb,
          const unsigned short* __restrict__ Kb,
          const unsigned short* __restrict__ Vb,
          unsigned short* Ob)
{
    const int qt = blockIdx.x;
    const int h  = blockIdx.y;
    const int t  = threadIdx.x;
    const int qr = t >> 2;
    const int c  = t & 3;
    const int s_q = qt * 64 + qr;
    const int hco = h * 64;

    __shared__ float Ks[64][68];
    __shared__ float Vs[64][68];
    __shared__ float Ps[64][68];

    float4 qreg[16];
    {
        const unsigned short* qp = Qb + (size_t)s_q * D_DIM + hco;
        #pragma unroll
        for (int i = 0; i < 16; ++i) {
            int off = (c * 16 + i * 4) & 63;
            ushort4 raw = *(const ushort4*)(qp + off);
            qreg[i] = make_float4(bf2f(raw.x), bf2f(raw.y), bf2f(raw.z), bf2f(raw.w));
        }
    }

    float m_run = NEG_BIG;
    float l_run = 0.f;
    float4 oacc[4];
    #pragma unroll
    for (int i = 0; i < 4; ++i) oacc[i] = make_float4(0.f, 0.f, 0.f, 0.f);

    for (int j = 0; j <= qt; ++j) {
        __syncthreads();
        #pragma unroll
        for (int r = 0; r < 4; ++r) {
            int cc  = t + r * 256;
            int kr  = cc >> 4;
            int col = (cc & 15) * 4;
            const unsigned short* kp = Kb + (size_t)(j * 64 + kr) * D_DIM + hco + col;
            const unsigned short* vp = Vb + (size_t)(j * 64 + kr) * D_DIM + hco + col;
            ushort4 kraw = *(const ushort4*)kp;
            ushort4 vraw = *(const ushort4*)vp;
            *(float4*)&Ks[kr][col] = make_float4(bf2f(kraw.x), bf2f(kraw.y), bf2f(kraw.z), bf2f(kraw.w));
            *(float4*)&Vs[kr][col] = make_float4(bf2f(vraw.x), bf2f(vraw.y), bf2f(vraw.z), bf2f(vraw.w));
        }
        __syncthreads();

        float p[16];
        float smax = NEG_BIG;
        #pragma unroll 4
        for (int kk = 0; kk < 16; ++kk) {
            int kc = c * 16 + kk;
            float dot = 0.f;
            #pragma unroll
            for (int i = 0; i < 16; ++i) {
                int off = (c * 16 + i * 4) & 63;
                float4 kv = *(const float4*)&Ks[kc][off];
                dot += qreg[i].x * kv.x + qreg[i].y * kv.y + qreg[i].z * kv.z + qreg[i].w * kv.w;
            }
            float sc = dot * 0.125f;
            if (j * 64 + kc > s_q) sc = NEG_BIG;
            p[kk] = sc;
            smax = fmaxf(smax, sc);
        }
        smax = fmaxf(smax, __shfl_xor(smax, 1));
        smax = fmaxf(smax, __shfl_xor(smax, 2));
        float m_new = fmaxf(m_run, smax);
        float alpha = __expf(fminf(fmaxf(m_run - m_new, -80.f), 0.f));
        float lsum = 0.f;
        #pragma unroll
        for (int kk = 0; kk < 16; ++kk) {
            float pe = __expf(fminf(fmaxf(p[kk] - m_new, -80.f), 0.f));
            Ps[qr][c * 16 + kk] = pe;
            lsum += pe;
        }
        lsum += __shfl_xor(lsum, 1);
        lsum += __shfl_xor(lsum, 2);
        l_run = l_run * alpha + lsum;
        m_run = m_new;
        #pragma unroll
        for (int i = 0; i < 4; ++i) {
            oacc[i].x *= alpha; oacc[i].y *= alpha;
            oacc[i].z *= alpha; oacc[i].w *= alpha;
        }
        __syncthreads();

        #pragma unroll 8
        for (int kc = 0; kc < 64; ++kc) {
            float pv = Ps[qr][kc];
            #pragma unroll
            for (int i = 0; i < 4; ++i) {
                float4 vv = *(const float4*)&Vs[kc][c * 16 + i * 4];
                oacc[i].x += pv * vv.x; oacc[i].y += pv * vv.y;
                oacc[i].z += pv * vv.z; oacc[i].w += pv * vv.w;
            }
        }
    }

    float inv_l = 1.f / l_run;
    unsigned short* op = Ob + (size_t)s_q * D_DIM + hco + c * 16;
    #pragma unroll
    for (int i = 0; i < 4; ++i) {
        op[i * 4 + 0] = f2b(oacc[i].x * inv_l);
        op[i * 4 + 1] = f2b(oacc[i].y * inv_l);
        op[i * 4 + 2] = f2b(oacc[i].z * inv_l);
        op[i * 4 + 3] = f2b(oacc[i].w * inv_l);
    }
}

// v1 passthrough -> out + SD elements, dtype per flag.
__global__ __launch_bounds__(256)
void copy_v1(const uint4* __restrict__ src, void* __restrict__ outBase,
             const int* __restrict__ flagp) {
    const int f = *flagp;
    const size_t SD = (size_t)S_LEN * D_DIM;
    const int n = f ? (int)(SD / 4) : (int)(SD / 8);   // uint4 chunks
    uint4* dst = (uint4*)((char*)outBase + SD * (f ? 4 : 2));
    int i = blockIdx.x * 256 + threadIdx.x;
    if (i < n) dst[i] = src[i];
}

extern "C" void kernel_launch(void* const* d_in, const int* in_sizes, int n_in,
                              void* d_out, int out_size, void* d_ws, size_t ws_size,
                              hipStream_t stream)
{
    const void* x    = d_in[0];
    const void* v1   = d_in[1];
    const void* Wq   = d_in[2];
    const void* Wk   = d_in[3];
    const void* Wv   = d_in[4];
    const void* Wout = d_in[5];
    const void* lam  = d_in[6];

    const size_t SD = (size_t)S_LEN * D_DIM;
    unsigned short* Qb = (unsigned short*)d_ws;          // internal bf16, 4 MB
    unsigned short* Kb = Qb + SD;                        // 4 MB
    unsigned short* Vb = Kb + SD;                        // 4 MB
    unsigned short* Ab = Qb;                             // alias (block-private RW)
    int* flagp = (int*)((char*)d_ws + 3 * SD * 2);       // @12 MB

    sniff<<<1, 64, 0, stream>>>((const unsigned int*)x, flagp);

    // Q/K/V projections (+ fused v-mix on z==2). A=x ext, B=weights ext, C internal.
    gemm_bt<<<dim3(D_DIM / 128, S_LEN / 128, 3), 256, 0, stream>>>(
        x, Wq, Wk, Wv, Qb, Kb, Vb, v1, lam, flagp, 1, 1, 0, D_DIM, D_DIM);
    norm_rope<<<dim3(S_LEN * NH / 4, 2), 256, 0, stream>>>(Qb, Kb);
    attn<<<dim3(S_LEN / 64, NH), 256, 0, stream>>>(Qb, Kb, Vb, Ab);
    // output projection: A internal, B=Wout ext, C=out ext.
    gemm_bt<<<dim3(D_DIM / 128, S_LEN / 128, 1), 256, 0, stream>>>(
        Ab, Wout, nullptr, nullptr, d_out, nullptr, nullptr, nullptr, nullptr,
        flagp, 0, 1, 1, D_DIM, D_DIM);
    copy_v1<<<dim3((unsigned)(SD / 4 + 255) / 256), 256, 0, stream>>>(
        (const uint4*)v1, d_out, flagp);
}

// Round 5
// 342.640 us; speedup vs baseline: 2.3130x; 2.3130x over previous
//
#include <hip/hip_runtime.h>
#include <hip/hip_bf16.h>

#define S_LEN 2048
#define D_DIM 1024
#define NH    16
#define NEG_BIG (-1.0e30f)

typedef __attribute__((ext_vector_type(8))) short bf16x8;
typedef __attribute__((ext_vector_type(4))) float f32x4;

__device__ __forceinline__ float bf2f(unsigned short h) {
    union { unsigned int u; float f; } v; v.u = ((unsigned int)h) << 16; return v.f;
}
__device__ __forceinline__ unsigned short f2b(float f) {   // RNE f32->bf16 raw bits
    union { float f; unsigned int u; } v; v.f = f;
    unsigned int u = v.u;
    return (unsigned short)((u + 0x7FFFu + ((u >> 16) & 1u)) >> 16);
}

// dtype sniff: external buffers f32 or bf16? (confirmed f32 in round 4, kept robust)
__global__ void sniff(const unsigned int* __restrict__ xw, int* __restrict__ flag) {
    int t = threadIdx.x;  // 64
    int cnt = 0;
    #pragma unroll
    for (int i = 0; i < 4; ++i) {
        unsigned int lo = xw[t * 4 + i] & 0xFFFFu;
        unsigned int e = (lo >> 7) & 0xFFu;
        cnt += (e >= 96u && e <= 130u) ? 1 : 0;
    }
    #pragma unroll
    for (int d = 1; d < 64; d <<= 1) cnt += __shfl_xor(cnt, d);
    if (t == 0) *flag = (cnt < 128) ? 1 : 0;   // 1 = external bufs are f32
}

// C[M,N] = A[M,K] * B[N,K]^T. Internal bf16; external operands decoded per flag.
__global__ __launch_bounds__(256, 2)
void gemm_bt(const void* __restrict__ A,
             const void* __restrict__ B0, const void* __restrict__ B1, const void* __restrict__ B2,
             void* __restrict__ C0, void* __restrict__ C1, void* __restrict__ C2,
             const void* __restrict__ vmix, const void* __restrict__ lam,
             const int* __restrict__ flagp,
             int aExt, int bExt, int cExt, int K, int N)
{
    const int f32f = *flagp;
    const int aF32 = aExt & f32f, bF32 = bExt & f32f, cF32 = cExt & f32f;
    const int which = blockIdx.z;
    const void* B = (which == 0) ? B0 : ((which == 1) ? B1 : B2);
    void* C = (which == 0) ? C0 : ((which == 1) ? C1 : C2);
    const int tn = blockIdx.x * 128;
    const int tm = blockIdx.y * 128;

    __shared__ unsigned short As[128][40];
    __shared__ unsigned short Bs[128][40];

    const int t    = threadIdx.x;
    const int lane = t & 63;
    const int wave = t >> 6;
    const int wm   = (wave >> 1) * 64;
    const int wn   = (wave & 1) * 64;
    const int lrow = lane & 15;
    const int quad = lane >> 4;

    f32x4 acc[4][4];
    #pragma unroll
    for (int i = 0; i < 4; ++i)
        #pragma unroll
        for (int j = 0; j < 4; ++j) {
            f32x4 z = {0.f, 0.f, 0.f, 0.f};
            acc[i][j] = z;
        }

    for (int k0 = 0; k0 < K; k0 += 32) {
        #pragma unroll
        for (int rep = 0; rep < 2; ++rep) {
            int cc  = t + rep * 256;
            int row = cc >> 2;
            int col = (cc & 3) * 8;
            size_t aoff = (size_t)(tm + row) * K + k0 + col;
            size_t boff = (size_t)(tn + row) * K + k0 + col;
            uint4 pa, pb;
            if (aF32) {
                const float* ap = (const float*)A + aoff;
                float4 lo = *(const float4*)ap, hi = *(const float4*)(ap + 4);
                pa.x = f2b(lo.x) | ((unsigned)f2b(lo.y) << 16);
                pa.y = f2b(lo.z) | ((unsigned)f2b(lo.w) << 16);
                pa.z = f2b(hi.x) | ((unsigned)f2b(hi.y) << 16);
                pa.w = f2b(hi.z) | ((unsigned)f2b(hi.w) << 16);
            } else {
                pa = *(const uint4*)((const unsigned short*)A + aoff);
            }
            if (bF32) {
                const float* bp = (const float*)B + boff;
                float4 lo = *(const float4*)bp, hi = *(const float4*)(bp + 4);
                pb.x = f2b(lo.x) | ((unsigned)f2b(lo.y) << 16);
                pb.y = f2b(lo.z) | ((unsigned)f2b(lo.w) << 16);
                pb.z = f2b(hi.x) | ((unsigned)f2b(hi.y) << 16);
                pb.w = f2b(hi.z) | ((unsigned)f2b(hi.w) << 16);
            } else {
                pb = *(const uint4*)((const unsigned short*)B + boff);
            }
            *(uint4*)(&As[row][col]) = pa;
            *(uint4*)(&Bs[row][col]) = pb;
        }
        __syncthreads();
        bf16x8 af[4], bfr[4];
        #pragma unroll
        for (int i = 0; i < 4; ++i)
            af[i] = *(const bf16x8*)(&As[wm + i * 16 + lrow][quad * 8]);
        #pragma unroll
        for (int j = 0; j < 4; ++j)
            bfr[j] = *(const bf16x8*)(&Bs[wn + j * 16 + lrow][quad * 8]);
        #pragma unroll
        for (int i = 0; i < 4; ++i)
            #pragma unroll
            for (int j = 0; j < 4; ++j)
                acc[i][j] = __builtin_amdgcn_mfma_f32_16x16x32_bf16(af[i], bfr[j], acc[i][j], 0, 0, 0);
        __syncthreads();
    }

    const bool domix = (which == 2) && (vmix != nullptr);
    float lamf = 0.f;
    if (domix)
        lamf = f32f ? *(const float*)lam : bf2f(((const unsigned short*)lam)[0]);

    #pragma unroll
    for (int i = 0; i < 4; ++i) {
        #pragma unroll
        for (int j = 0; j < 4; ++j) {
            #pragma unroll
            for (int r = 0; r < 4; ++r) {
                int cm = tm + wm + i * 16 + quad * 4 + r;   // row = quad*4+reg (m89/m91)
                int cn = tn + wn + j * 16 + lrow;           // col = lane&15
                size_t idx = (size_t)cm * N + cn;
                float v = acc[i][j][r];
                if (domix) {
                    float vf = f32f ? ((const float*)vmix)[idx]
                                    : bf2f(((const unsigned short*)vmix)[idx]);
                    v = (1.f - lamf) * v + lamf * vf;
                }
                if (cF32) ((float*)C)[idx] = v;
                else      ((unsigned short*)C)[idx] = f2b(v);
            }
        }
    }
}

// fused per-head RMSNorm + RoPE, in place on internal bf16 buffers.
__global__ __launch_bounds__(256)
void norm_rope(unsigned short* __restrict__ Qb, unsigned short* __restrict__ Kb)
{
    unsigned short* X = (blockIdx.y == 0) ? Qb : Kb;
    const int t = threadIdx.x;
    const int wave = t >> 6, lane = t & 63;
    const int row = blockIdx.x * 4 + wave;
    const int s = row >> 4;
    const int h = row & 15;
    unsigned short* xp = X + (size_t)s * D_DIM + h * 64;

    float x = bf2f(xp[lane]);
    float ss = x * x;
    #pragma unroll
    for (int d = 1; d < 64; d <<= 1) ss += __shfl_xor(ss, d);
    float rms = rsqrtf(ss * (1.f / 64.f) + 1.1920929e-7f);
    float xn = x * rms;
    float part = __shfl_xor(xn, 32);
    int i = lane & 31;
    float inv = exp2f(-0.41524101186092030f * (float)i);     // 10000^(-2i/64)
    float ang = (float)s * inv;
    float sv, cv;
    sincosf(ang, &sv, &cv);
    float o = xn * cv + ((lane < 32) ? part * sv : -part * sv);
    xp[lane] = f2b(o);
}

// MFMA flash attention. grid (32 paired q-tiles, NH), block 256 (4 waves x 16 q-rows).
// Per K-tile: stage K row-major + V transposed (Vt[d][key]) in LDS;
// QK^T: A=Q-rows, B=K-rows (same operand pattern as gemm_bt, HW-verified r4);
// online softmax in C-layout; P -> per-wave LDS -> A-frags; PV: B=Vt rows.
// Ob may alias Qb: each block reads only (its rows x its head cols) and writes same.
__global__ __launch_bounds__(256, 2)
void attn_mfma(const unsigned short* Qb,
               const unsigned short* __restrict__ Kb,
               const unsigned short* __restrict__ Vb,
               unsigned short* Ob)
{
    const int bx = blockIdx.x;
    const int qt = (bx & 1) ? (31 - (bx >> 1)) : (bx >> 1);  // pair big+small tiles
    const int h  = blockIdx.y;
    const int t  = threadIdx.x;
    const int w  = t >> 6;
    const int l  = t & 63;
    const int l15  = l & 15;
    const int quad = l >> 4;
    const int hco  = h * 64;

    __shared__ unsigned short Ks[64][72];       // 72: 16B-aligned rows, banks rotate by 4dw/row
    __shared__ unsigned short Vt[64][72];       // V transposed: Vt[d][key]
    __shared__ unsigned short Ps[4][16][72];    // per-wave P tile

    // Q A-frags for this wave's 16 rows: A[m=l15][k=quad*8+j], chunks k0=0,32
    const unsigned short* qrow = Qb + (size_t)(qt * 64 + w * 16 + l15) * D_DIM + hco;
    bf16x8 qf0 = *(const bf16x8*)(qrow + quad * 8);
    bf16x8 qf1 = *(const bf16x8*)(qrow + 32 + quad * 8);

    f32x4 oac[4];
    #pragma unroll
    for (int nt = 0; nt < 4; ++nt) { f32x4 z = {0.f,0.f,0.f,0.f}; oac[nt] = z; }
    float m_run[4], l_run[4];
    #pragma unroll
    for (int r = 0; r < 4; ++r) { m_run[r] = NEG_BIG; l_run[r] = 0.f; }

    const int kr = t >> 2;          // staging: my key row
    const int g  = t & 3;           // staging: my 16-col group
    const int dc = g * 16;

    for (int j = 0; j <= qt; ++j) {
        __syncthreads();
        {
            const unsigned short* krow = Kb + (size_t)(j * 64 + kr) * D_DIM + hco + dc;
            const unsigned short* vrow = Vb + (size_t)(j * 64 + kr) * D_DIM + hco + dc;
            *(uint4*)&Ks[kr][dc]     = *(const uint4*)krow;
            *(uint4*)&Ks[kr][dc + 8] = *(const uint4*)(krow + 8);
            union { uint4 q[2]; unsigned short u[16]; } vb;
            vb.q[0] = *(const uint4*)vrow;
            vb.q[1] = *(const uint4*)(vrow + 8);
            #pragma unroll
            for (int i = 0; i < 16; ++i) {      // d-rotation 2g: concurrent rows differ !=0 mod 8
                int e = (i + 2 * g) & 15;
                Vt[dc + e][kr] = vb.u[e];
            }
        }
        __syncthreads();

        // S = Q K^T (16 rows x 64 keys), f32 accum
        f32x4 sac[4];
        #pragma unroll
        for (int nt = 0; nt < 4; ++nt) {
            f32x4 z = {0.f,0.f,0.f,0.f};
            bf16x8 kf0 = *(const bf16x8*)&Ks[nt * 16 + l15][quad * 8];
            z = __builtin_amdgcn_mfma_f32_16x16x32_bf16(qf0, kf0, z, 0, 0, 0);
            bf16x8 kf1 = *(const bf16x8*)&Ks[nt * 16 + l15][32 + quad * 8];
            z = __builtin_amdgcn_mfma_f32_16x16x32_bf16(qf1, kf1, z, 0, 0, 0);
            sac[nt] = z;
        }

        // scale + causal mask + row max (C-layout: row=quad*4+r, col=nt*16+l15)
        float sv[4][4];
        float mx[4] = {NEG_BIG, NEG_BIG, NEG_BIG, NEG_BIG};
        #pragma unroll
        for (int nt = 0; nt < 4; ++nt) {
            int key_g = j * 64 + nt * 16 + l15;
            #pragma unroll
            for (int r = 0; r < 4; ++r) {
                int row_g = qt * 64 + w * 16 + quad * 4 + r;
                float s = sac[nt][r] * 0.125f;
                if (key_g > row_g) s = NEG_BIG;
                sv[nt][r] = s;
                mx[r] = fmaxf(mx[r], s);
            }
        }
        #pragma unroll
        for (int r = 0; r < 4; ++r) {
            #pragma unroll
            for (int d = 1; d < 16; d <<= 1) mx[r] = fmaxf(mx[r], __shfl_xor(mx[r], d));
        }

        float alpha[4], ls[4];
        #pragma unroll
        for (int r = 0; r < 4; ++r) {
            float mn = fmaxf(m_run[r], mx[r]);
            alpha[r] = __expf(fminf(fmaxf(m_run[r] - mn, -80.f), 0.f));
            m_run[r] = mn;
            ls[r] = 0.f;
        }
        #pragma unroll
        for (int nt = 0; nt < 4; ++nt) {
            #pragma unroll
            for (int r = 0; r < 4; ++r) {
                float pe = __expf(fminf(fmaxf(sv[nt][r] - m_run[r], -80.f), 0.f));
                ls[r] += pe;
                Ps[w][quad * 4 + r][nt * 16 + l15] = f2b(pe);
            }
        }
        #pragma unroll
        for (int r = 0; r < 4; ++r) {
            #pragma unroll
            for (int d = 1; d < 16; d <<= 1) ls[r] += __shfl_xor(ls[r], d);
            l_run[r] = l_run[r] * alpha[r] + ls[r];
        }
        #pragma unroll
        for (int nt = 0; nt < 4; ++nt) {
            #pragma unroll
            for (int r = 0; r < 4; ++r) oac[nt][r] *= alpha[r];
        }

        // P A-frags (per-wave LDS round-trip, m120 pattern) then PV
        bf16x8 pf0 = *(const bf16x8*)&Ps[w][l15][quad * 8];
        bf16x8 pf1 = *(const bf16x8*)&Ps[w][l15][32 + quad * 8];
        #pragma unroll
        for (int nt = 0; nt < 4; ++nt) {
            bf16x8 vf0 = *(const bf16x8*)&Vt[nt * 16 + l15][quad * 8];
            oac[nt] = __builtin_amdgcn_mfma_f32_16x16x32_bf16(pf0, vf0, oac[nt], 0, 0, 0);
            bf16x8 vf1 = *(const bf16x8*)&Vt[nt * 16 + l15][32 + quad * 8];
            oac[nt] = __builtin_amdgcn_mfma_f32_16x16x32_bf16(pf1, vf1, oac[nt], 0, 0, 0);
        }
    }

    float inv[4];
    #pragma unroll
    for (int r = 0; r < 4; ++r) inv[r] = 1.f / l_run[r];   // >= 1 (diagonal key unmasked)
    #pragma unroll
    for (int nt = 0; nt < 4; ++nt) {
        #pragma unroll
        for (int r = 0; r < 4; ++r) {
            int row_g = qt * 64 + w * 16 + quad * 4 + r;
            Ob[(size_t)row_g * D_DIM + hco + nt * 16 + l15] = f2b(oac[nt][r] * inv[r]);
        }
    }
}

// v1 passthrough -> out + SD elements, dtype per flag.
__global__ __launch_bounds__(256)
void copy_v1(const uint4* __restrict__ src, void* __restrict__ outBase,
             const int* __restrict__ flagp) {
    const int f = *flagp;
    const size_t SD = (size_t)S_LEN * D_DIM;
    const int n = f ? (int)(SD / 4) : (int)(SD / 8);   // uint4 chunks
    uint4* dst = (uint4*)((char*)outBase + SD * (f ? 4 : 2));
    int i = blockIdx.x * 256 + threadIdx.x;
    if (i < n) dst[i] = src[i];
}

extern "C" void kernel_launch(void* const* d_in, const int* in_sizes, int n_in,
                              void* d_out, int out_size, void* d_ws, size_t ws_size,
                              hipStream_t stream)
{
    const void* x    = d_in[0];
    const void* v1   = d_in[1];
    const void* Wq   = d_in[2];
    const void* Wk   = d_in[3];
    const void* Wv   = d_in[4];
    const void* Wout = d_in[5];
    const void* lam  = d_in[6];

    const size_t SD = (size_t)S_LEN * D_DIM;
    unsigned short* Qb = (unsigned short*)d_ws;          // internal bf16, 4 MB
    unsigned short* Kb = Qb + SD;                        // 4 MB
    unsigned short* Vb = Kb + SD;                        // 4 MB
    unsigned short* Ab = Qb;                             // alias (block-private RW)
    int* flagp = (int*)((char*)d_ws + 3 * SD * 2);       // @12 MB

    sniff<<<1, 64, 0, stream>>>((const unsigned int*)x, flagp);

    // Q/K/V projections (+ fused v-mix on z==2). A=x ext, B=weights ext, C internal.
    gemm_bt<<<dim3(D_DIM / 128, S_LEN / 128, 3), 256, 0, stream>>>(
        x, Wq, Wk, Wv, Qb, Kb, Vb, v1, lam, flagp, 1, 1, 0, D_DIM, D_DIM);
    norm_rope<<<dim3(S_LEN * NH / 4, 2), 256, 0, stream>>>(Qb, Kb);
    attn_mfma<<<dim3(S_LEN / 64, NH), 256, 0, stream>>>(Qb, Kb, Vb, Ab);
    // output projection: A internal, B=Wout ext, C=out ext.
    gemm_bt<<<dim3(D_DIM / 128, S_LEN / 128, 1), 256, 0, stream>>>(
        Ab, Wout, nullptr, nullptr, d_out, nullptr, nullptr, nullptr, nullptr,
        flagp, 0, 1, 1, D_DIM, D_DIM);
    copy_v1<<<dim3((unsigned)(SD / 4 + 255) / 256), 256, 0, stream>>>(
        (const uint4*)v1, d_out, flagp);
}

// Round 6
// 233.727 us; speedup vs baseline: 3.3908x; 1.4660x over previous
//
#include <hip/hip_runtime.h>
#include <hip/hip_bf16.h>

#define S_LEN 2048
#define D_DIM 1024
#define NH    16
#define NEG_BIG (-1.0e30f)

typedef __attribute__((ext_vector_type(8))) short bf16x8;
typedef __attribute__((ext_vector_type(4))) float f32x4;

__device__ __forceinline__ float bf2f(unsigned short h) {
    union { unsigned int u; float f; } v; v.u = ((unsigned int)h) << 16; return v.f;
}
__device__ __forceinline__ unsigned short f2b(float f) {   // RNE f32->bf16 raw bits
    union { float f; unsigned int u; } v; v.f = f;
    unsigned int u = v.u;
    return (unsigned short)((u + 0x7FFFu + ((u >> 16) & 1u)) >> 16);
}

// dtype sniff (confirmed f32 in round 4; kept for robustness)
__global__ void sniff(const unsigned int* __restrict__ xw, int* __restrict__ flag) {
    int t = threadIdx.x;  // 64
    int cnt = 0;
    #pragma unroll
    for (int i = 0; i < 4; ++i) {
        unsigned int lo = xw[t * 4 + i] & 0xFFFFu;
        unsigned int e = (lo >> 7) & 0xFFu;
        cnt += (e >= 96u && e <= 130u) ? 1 : 0;
    }
    #pragma unroll
    for (int d = 1; d < 64; d <<= 1) cnt += __shfl_xor(cnt, d);
    if (t == 0) *flag = (cnt < 128) ? 1 : 0;   // 1 = external bufs are f32
}

// one-shot f32 -> bf16 conversion of x + 4 weights (only when flag==1).
// grid (1024, 5); z: 0=x (2M elems), 1..4 = Wq,Wk,Wv,Wout (1M each).
__global__ __launch_bounds__(256)
void to_bf16(const float* __restrict__ x,  const float* __restrict__ wq,
             const float* __restrict__ wk, const float* __restrict__ wv,
             const float* __restrict__ wo,
             unsigned short* __restrict__ xb,  unsigned short* __restrict__ wqb,
             unsigned short* __restrict__ wkb, unsigned short* __restrict__ wvb,
             unsigned short* __restrict__ wob,
             const int* __restrict__ flagp)
{
    if (!*flagp) return;
    const int z = blockIdx.y;
    const float* s; unsigned short* d; int n;
    switch (z) {
        case 0: s = x;  d = xb;  n = S_LEN * D_DIM; break;
        case 1: s = wq; d = wqb; n = D_DIM * D_DIM; break;
        case 2: s = wk; d = wkb; n = D_DIM * D_DIM; break;
        case 3: s = wv; d = wvb; n = D_DIM * D_DIM; break;
        default: s = wo; d = wob; n = D_DIM * D_DIM; break;
    }
    int i8 = blockIdx.x * 256 + threadIdx.x;
    if (i8 * 8 >= n) return;
    const float* sp = s + (size_t)i8 * 8;
    float4 lo = *(const float4*)sp, hi = *(const float4*)(sp + 4);
    uint4 p;
    p.x = f2b(lo.x) | ((unsigned)f2b(lo.y) << 16);
    p.y = f2b(lo.z) | ((unsigned)f2b(lo.w) << 16);
    p.z = f2b(hi.x) | ((unsigned)f2b(hi.y) << 16);
    p.w = f2b(hi.z) | ((unsigned)f2b(hi.w) << 16);
    *(uint4*)(d + (size_t)i8 * 8) = p;
}

// C[M,N] = A[M,K] * B[N,K]^T. All MFMA inputs bf16 (externals pre-converted;
// device-side select orig-vs-converted per flag). cTransMask bit 'which':
// store C transposed as Ct[cn][cm] with row stride Mt (used for V: Vt_g[dg][s]).
__global__ __launch_bounds__(256, 2)
void gemm_bt(const void* __restrict__ A,  const unsigned short* __restrict__ Aconv,
             const void* __restrict__ B0, const void* __restrict__ B1, const void* __restrict__ B2,
             const unsigned short* __restrict__ Bc0, const unsigned short* __restrict__ Bc1,
             const unsigned short* __restrict__ Bc2,
             void* __restrict__ C0, void* __restrict__ C1, void* __restrict__ C2,
             const void* __restrict__ vmix, const void* __restrict__ lam,
             const int* __restrict__ flagp,
             int aExt, int bExt, int cExt, int cTransMask, int K, int N, int Mt)
{
    const int f32f = *flagp;
    const int which = blockIdx.z;
    const void* Bo = (which == 0) ? B0 : ((which == 1) ? B1 : B2);
    const unsigned short* Bcv = (which == 0) ? Bc0 : ((which == 1) ? Bc1 : Bc2);
    const unsigned short* Ap = (aExt && f32f) ? Aconv : (const unsigned short*)A;
    const unsigned short* Bp = (bExt && f32f) ? Bcv   : (const unsigned short*)Bo;
    void* C = (which == 0) ? C0 : ((which == 1) ? C1 : C2);
    const int cF32  = cExt & f32f;
    const int cTr   = (cTransMask >> which) & 1;
    const int tn = blockIdx.x * 128;
    const int tm = blockIdx.y * 128;

    __shared__ unsigned short As[128][40];
    __shared__ unsigned short Bs[128][40];

    const int t    = threadIdx.x;
    const int lane = t & 63;
    const int wave = t >> 6;
    const int wm   = (wave >> 1) * 64;
    const int wn   = (wave & 1) * 64;
    const int lrow = lane & 15;
    const int quad = lane >> 4;

    f32x4 acc[4][4];
    #pragma unroll
    for (int i = 0; i < 4; ++i)
        #pragma unroll
        for (int j = 0; j < 4; ++j) {
            f32x4 z = {0.f, 0.f, 0.f, 0.f};
            acc[i][j] = z;
        }

    for (int k0 = 0; k0 < K; k0 += 32) {
        #pragma unroll
        for (int rep = 0; rep < 2; ++rep) {
            int cc  = t + rep * 256;
            int row = cc >> 2;
            int col = (cc & 3) * 8;
            *(uint4*)(&As[row][col]) = *(const uint4*)(Ap + (size_t)(tm + row) * K + k0 + col);
            *(uint4*)(&Bs[row][col]) = *(const uint4*)(Bp + (size_t)(tn + row) * K + k0 + col);
        }
        __syncthreads();
        bf16x8 af[4], bfr[4];
        #pragma unroll
        for (int i = 0; i < 4; ++i)
            af[i] = *(const bf16x8*)(&As[wm + i * 16 + lrow][quad * 8]);
        #pragma unroll
        for (int j = 0; j < 4; ++j)
            bfr[j] = *(const bf16x8*)(&Bs[wn + j * 16 + lrow][quad * 8]);
        #pragma unroll
        for (int i = 0; i < 4; ++i)
            #pragma unroll
            for (int j = 0; j < 4; ++j)
                acc[i][j] = __builtin_amdgcn_mfma_f32_16x16x32_bf16(af[i], bfr[j], acc[i][j], 0, 0, 0);
        __syncthreads();
    }

    const bool domix = (which == 2) && (vmix != nullptr);
    float lamf = 0.f;
    if (domix)
        lamf = f32f ? *(const float*)lam : bf2f(((const unsigned short*)lam)[0]);

    #pragma unroll
    for (int i = 0; i < 4; ++i) {
        #pragma unroll
        for (int j = 0; j < 4; ++j) {
            int cm0 = tm + wm + i * 16 + quad * 4;      // row base = quad*4 (m89/m91)
            int cn  = tn + wn + j * 16 + lrow;          // col = lane&15
            float vals[4];
            #pragma unroll
            for (int r = 0; r < 4; ++r) {
                size_t idx = (size_t)(cm0 + r) * N + cn;
                float v = acc[i][j][r];
                if (domix) {
                    float vf = f32f ? ((const float*)vmix)[idx]
                                    : bf2f(((const unsigned short*)vmix)[idx]);
                    v = (1.f - lamf) * v + lamf * vf;
                }
                vals[r] = v;
            }
            if (cTr) {
                // Ct[cn][cm0..cm0+3], one 8B store (cm0 % 4 == 0)
                ushort4 pk;
                pk.x = f2b(vals[0]); pk.y = f2b(vals[1]);
                pk.z = f2b(vals[2]); pk.w = f2b(vals[3]);
                *(ushort4*)((unsigned short*)C + (size_t)cn * Mt + cm0) = pk;
            } else {
                #pragma unroll
                for (int r = 0; r < 4; ++r) {
                    size_t idx = (size_t)(cm0 + r) * N + cn;
                    if (cF32) ((float*)C)[idx] = vals[r];
                    else      ((unsigned short*)C)[idx] = f2b(vals[r]);
                }
            }
        }
    }
}

// fused per-head RMSNorm + RoPE, in place on internal bf16 buffers (Q,K only).
__global__ __launch_bounds__(256)
void norm_rope(unsigned short* __restrict__ Qb, unsigned short* __restrict__ Kb)
{
    unsigned short* X = (blockIdx.y == 0) ? Qb : Kb;
    const int t = threadIdx.x;
    const int wave = t >> 6, lane = t & 63;
    const int row = blockIdx.x * 4 + wave;
    const int s = row >> 4;
    const int h = row & 15;
    unsigned short* xp = X + (size_t)s * D_DIM + h * 64;

    float x = bf2f(xp[lane]);
    float ss = x * x;
    #pragma unroll
    for (int d = 1; d < 64; d <<= 1) ss += __shfl_xor(ss, d);
    float rms = rsqrtf(ss * (1.f / 64.f) + 1.1920929e-7f);
    float xn = x * rms;
    float part = __shfl_xor(xn, 32);
    int i = lane & 31;
    float inv = exp2f(-0.41524101186092030f * (float)i);     // 10000^(-2i/64)
    float ang = (float)s * inv;
    float sv, cv;
    sincosf(ang, &sv, &cv);
    float o = xn * cv + ((lane < 32) ? part * sv : -part * sv);
    xp[lane] = f2b(o);
}

// MFMA flash attention. V arrives PRE-TRANSPOSED globally (Vt_g[dg][s]) so
// staging is pure b128 (no scalar transpose). Next K/V tile prefetched into
// registers during compute. grid (32 paired q-tiles, NH), block 256.
__global__ __launch_bounds__(256, 2)
void attn_mfma(const unsigned short* Qb,
               const unsigned short* __restrict__ Kb,
               const unsigned short* __restrict__ Vtg,
               unsigned short* Ob)
{
    const int bx = blockIdx.x;
    const int qt = (bx & 1) ? (31 - (bx >> 1)) : (bx >> 1);  // pair big+small tiles
    const int h  = blockIdx.y;
    const int t  = threadIdx.x;
    const int w  = t >> 6;
    const int l  = t & 63;
    const int l15  = l & 15;
    const int quad = l >> 4;
    const int hco  = h * 64;

    __shared__ unsigned short Ks[64][72];
    __shared__ unsigned short Vt[64][72];       // Vt[d][key]
    __shared__ unsigned short Ps[4][16][72];    // per-wave P tile

    // Q A-frags: A[m=l15][k=quad*8+j], k-chunks 0 and 32
    const unsigned short* qrow = Qb + (size_t)(qt * 64 + w * 16 + l15) * D_DIM + hco;
    bf16x8 qf0 = *(const bf16x8*)(qrow + quad * 8);
    bf16x8 qf1 = *(const bf16x8*)(qrow + 32 + quad * 8);

    f32x4 oac[4];
    #pragma unroll
    for (int nt = 0; nt < 4; ++nt) { f32x4 z = {0.f,0.f,0.f,0.f}; oac[nt] = z; }
    float m_run[4], l_run[4];
    #pragma unroll
    for (int r = 0; r < 4; ++r) { m_run[r] = NEG_BIG; l_run[r] = 0.f; }

    const int rr = t >> 2;          // staging row (K: key row; Vt: d row)
    const int dc = (t & 3) * 16;    // 16-col group

    const unsigned short* kbase = Kb  + (size_t)rr * D_DIM + hco + dc;          // + j*64*D_DIM
    const unsigned short* vbase = Vtg + (size_t)(hco + rr) * S_LEN + dc;        // + j*64

    uint4 ka0, ka1, va0, va1;
    ka0 = *(const uint4*)kbase;  ka1 = *(const uint4*)(kbase + 8);
    va0 = *(const uint4*)vbase;  va1 = *(const uint4*)(vbase + 8);

    for (int j = 0; j <= qt; ++j) {
        __syncthreads();                      // previous tile's LDS readers done
        *(uint4*)&Ks[rr][dc]     = ka0;
        *(uint4*)&Ks[rr][dc + 8] = ka1;
        *(uint4*)&Vt[rr][dc]     = va0;
        *(uint4*)&Vt[rr][dc + 8] = va1;
        __syncthreads();
        if (j < qt) {                         // prefetch next tile into regs
            const unsigned short* kp = kbase + (size_t)(j + 1) * 64 * D_DIM;
            const unsigned short* vp = vbase + (size_t)(j + 1) * 64;
            ka0 = *(const uint4*)kp;  ka1 = *(const uint4*)(kp + 8);
            va0 = *(const uint4*)vp;  va1 = *(const uint4*)(vp + 8);
        }

        // S = Q K^T (16 rows x 64 keys)
        f32x4 sac[4];
        #pragma unroll
        for (int nt = 0; nt < 4; ++nt) {
            f32x4 z = {0.f,0.f,0.f,0.f};
            bf16x8 kf0 = *(const bf16x8*)&Ks[nt * 16 + l15][quad * 8];
            z = __builtin_amdgcn_mfma_f32_16x16x32_bf16(qf0, kf0, z, 0, 0, 0);
            bf16x8 kf1 = *(const bf16x8*)&Ks[nt * 16 + l15][32 + quad * 8];
            z = __builtin_amdgcn_mfma_f32_16x16x32_bf16(qf1, kf1, z, 0, 0, 0);
            sac[nt] = z;
        }

        // scale + causal mask + row max (C-layout: row=quad*4+r, col=nt*16+l15)
        float sv[4][4];
        float mx[4] = {NEG_BIG, NEG_BIG, NEG_BIG, NEG_BIG};
        #pragma unroll
        for (int nt = 0; nt < 4; ++nt) {
            int key_g = j * 64 + nt * 16 + l15;
            #pragma unroll
            for (int r = 0; r < 4; ++r) {
                int row_g = qt * 64 + w * 16 + quad * 4 + r;
                float s = sac[nt][r] * 0.125f;
                if (key_g > row_g) s = NEG_BIG;
                sv[nt][r] = s;
                mx[r] = fmaxf(mx[r], s);
            }
        }
        #pragma unroll
        for (int r = 0; r < 4; ++r) {
            #pragma unroll
            for (int d = 1; d < 16; d <<= 1) mx[r] = fmaxf(mx[r], __shfl_xor(mx[r], d));
        }

        float alpha[4], ls[4];
        #pragma unroll
        for (int r = 0; r < 4; ++r) {
            float mn = fmaxf(m_run[r], mx[r]);
            alpha[r] = __expf(fminf(fmaxf(m_run[r] - mn, -80.f), 0.f));
            m_run[r] = mn;
            ls[r] = 0.f;
        }
        #pragma unroll
        for (int nt = 0; nt < 4; ++nt) {
            #pragma unroll
            for (int r = 0; r < 4; ++r) {
                float pe = __expf(fminf(fmaxf(sv[nt][r] - m_run[r], -80.f), 0.f));
                ls[r] += pe;
                Ps[w][quad * 4 + r][nt * 16 + l15] = f2b(pe);
            }
        }
        #pragma unroll
        for (int r = 0; r < 4; ++r) {
            #pragma unroll
            for (int d = 1; d < 16; d <<= 1) ls[r] += __shfl_xor(ls[r], d);
            l_run[r] = l_run[r] * alpha[r] + ls[r];
        }
        #pragma unroll
        for (int nt = 0; nt < 4; ++nt) {
            #pragma unroll
            for (int r = 0; r < 4; ++r) oac[nt][r] *= alpha[r];
        }

        // P A-frags (per-wave LDS round-trip, HW-verified r5) then PV
        bf16x8 pf0 = *(const bf16x8*)&Ps[w][l15][quad * 8];
        bf16x8 pf1 = *(const bf16x8*)&Ps[w][l15][32 + quad * 8];
        #pragma unroll
        for (int nt = 0; nt < 4; ++nt) {
            bf16x8 vf0 = *(const bf16x8*)&Vt[nt * 16 + l15][quad * 8];
            oac[nt] = __builtin_amdgcn_mfma_f32_16x16x32_bf16(pf0, vf0, oac[nt], 0, 0, 0);
            bf16x8 vf1 = *(const bf16x8*)&Vt[nt * 16 + l15][32 + quad * 8];
            oac[nt] = __builtin_amdgcn_mfma_f32_16x16x32_bf16(pf1, vf1, oac[nt], 0, 0, 0);
        }
    }

    float inv[4];
    #pragma unroll
    for (int r = 0; r < 4; ++r) inv[r] = 1.f / l_run[r];   // >= 1 (diagonal unmasked)
    #pragma unroll
    for (int nt = 0; nt < 4; ++nt) {
        #pragma unroll
        for (int r = 0; r < 4; ++r) {
            int row_g = qt * 64 + w * 16 + quad * 4 + r;
            Ob[(size_t)row_g * D_DIM + hco + nt * 16 + l15] = f2b(oac[nt][r] * inv[r]);
        }
    }
}

// v1 passthrough -> out + SD elements, dtype per flag.
__global__ __launch_bounds__(256)
void copy_v1(const uint4* __restrict__ src, void* __restrict__ outBase,
             const int* __restrict__ flagp) {
    const int f = *flagp;
    const size_t SD = (size_t)S_LEN * D_DIM;
    const int n = f ? (int)(SD / 4) : (int)(SD / 8);   // uint4 chunks
    uint4* dst = (uint4*)((char*)outBase + SD * (f ? 4 : 2));
    int i = blockIdx.x * 256 + threadIdx.x;
    if (i < n) dst[i] = src[i];
}

extern "C" void kernel_launch(void* const* d_in, const int* in_sizes, int n_in,
                              void* d_out, int out_size, void* d_ws, size_t ws_size,
                              hipStream_t stream)
{
    const void* x    = d_in[0];
    const void* v1   = d_in[1];
    const void* Wq   = d_in[2];
    const void* Wk   = d_in[3];
    const void* Wv   = d_in[4];
    const void* Wout = d_in[5];
    const void* lam  = d_in[6];

    const size_t SD = (size_t)S_LEN * D_DIM;
    unsigned short* Qb  = (unsigned short*)d_ws;         // internal bf16, 4 MB
    unsigned short* Kb  = Qb + SD;                       // 4 MB
    unsigned short* Vtg = Kb + SD;                       // V transposed [D_DIM][S_LEN], 4 MB
    unsigned short* Ab  = Qb;                            // alias (block-private RW)
    int* flagp = (int*)((char*)d_ws + 3 * SD * 2);       // @12 MB

    // bf16 scratch copies (only touched when flag==1, i.e. externals are f32 and
    // d_out is f32-sized: y slot 8 MB @ +0, v1 slot 8 MB @ +SD*4; both overwritten later)
    unsigned short* Wqb   = (unsigned short*)d_out;                    // 2 MB
    unsigned short* Wkb   = Wqb + (size_t)D_DIM * D_DIM;               // 2 MB
    unsigned short* Wvb   = Wkb + (size_t)D_DIM * D_DIM;               // 2 MB
    unsigned short* xb    = (unsigned short*)((char*)d_out + SD * 4);  // 4 MB
    unsigned short* Woutb = xb + SD;                                   // 2 MB

    sniff<<<1, 64, 0, stream>>>((const unsigned int*)x, flagp);
    to_bf16<<<dim3(1024, 5), 256, 0, stream>>>(
        (const float*)x, (const float*)Wq, (const float*)Wk, (const float*)Wv, (const float*)Wout,
        xb, Wqb, Wkb, Wvb, Woutb, flagp);

    // Q/K/V projections (+ fused v-mix; V stored transposed via cTransMask bit 2)
    gemm_bt<<<dim3(D_DIM / 128, S_LEN / 128, 3), 256, 0, stream>>>(
        x, xb, Wq, Wk, Wv, Wqb, Wkb, Wvb,
        Qb, Kb, Vtg, v1, lam, flagp, 1, 1, 0, 4, D_DIM, D_DIM, S_LEN);
    norm_rope<<<dim3(S_LEN * NH / 4, 2), 256, 0, stream>>>(Qb, Kb);
    attn_mfma<<<dim3(S_LEN / 64, NH), 256, 0, stream>>>(Qb, Kb, Vtg, Ab);
    // output projection: A internal bf16, B=Wout (converted), C=out f32 (y slot)
    gemm_bt<<<dim3(D_DIM / 128, S_LEN / 128, 1), 256, 0, stream>>>(
        Ab, Ab, Wout, nullptr, nullptr, Woutb, nullptr, nullptr,
        d_out, nullptr, nullptr, nullptr, nullptr, flagp, 0, 1, 1, 0, D_DIM, D_DIM, S_LEN);
    copy_v1<<<dim3((unsigned)(SD / 4 + 255) / 256), 256, 0, stream>>>(
        (const uint4*)v1, d_out, flagp);
}